// Round 1
// baseline (335.477 us; speedup 1.0000x reference)
//
#include <hip/hip_runtime.h>

// Problem constants (fixed by setup_inputs)
#define B_      4
#define C_UNI   64
#define H_      512
#define W_      512
#define HW      (H_ * W_)        // 262144 = 2^18
#define HW_LOG2 18
#define N_PIX   (B_ * HW)        // 1,048,576 pixels
#define NBLOCKS 2048             // N_PIX / 2 px-per-thread / 256 threads
#define IGNORE_INDEX 255

typedef float f32x2 __attribute__((ext_vector_type(2)));

// R5 theory: previous best (335 us) ran uni_ce_main at ~1.7 TB/s (26% of HBM)
// despite a 43 us memory roofline. Suspected cause: 16 accumulators + 16
// in-flight f32x4 loads pushed VGPR > 128 -> only ~8-12 waves/CU and
// pressure-serialized loads -> latency-bound, not BW-bound.
// This version: 2 px/thread (f32x2 loads), 2048 blocks, single accumulator
// bank, __launch_bounds__(256,8) -> VGPR<=64, 32 waves/CU, 8 loads in
// flight/wave. Deterministic per-block partials, zero atomics (R4 lesson:
// last-block fusion with device-scope atomics regressed +46 us).

__global__ __launch_bounds__(256, 8) void uni_ce_main(
    const float* __restrict__ inp,      // [B, C_UNI, H, W]
    const int*   __restrict__ targets,  // [B, H, W]
    const int*   __restrict__ gids,     // [C_UNI]
    float2*      __restrict__ partial)  // [NBLOCKS] {loss_sum, valid_cnt}
{
    __shared__ int s_gid[C_UNI];
    const int tid = threadIdx.x;
    if (tid < C_UNI) s_gid[tid] = gids[tid];
    __syncthreads();

    const int g    = blockIdx.x * blockDim.x + tid;   // [0, N_PIX/2)
    const int base = g << 1;                          // first pixel index
    const int b    = base >> HW_LOG2;                 // block-uniform (512 px/block)
    const int pix  = base & (HW - 1);

    const int2 t2 = *(const int2*)(targets + base);

    const float* p = inp + (((size_t)(b * C_UNI)) << HW_LOG2) + pix;

    float den0 = 0.f, den1 = 0.f, num0 = 0.f, num1 = 0.f;

    #pragma unroll 8
    for (int c = 0; c < C_UNI; ++c) {
        const f32x2 x = __builtin_nontemporal_load(
            (const f32x2*)(p + ((size_t)c << HW_LOG2)));
        const float e0 = __expf(x.x);
        const float e1 = __expf(x.y);
        den0 += e0;
        den1 += e1;
        const int gc = s_gid[c];                      // wave-uniform broadcast
        if (gc == t2.x) num0 += e0;
        if (gc == t2.y) num1 += e1;
    }

    float loss = 0.f, cnt = 0.f;
    if (t2.x != IGNORE_INDEX) { loss += __logf(den0) - __logf(num0); cnt += 1.f; }
    if (t2.y != IGNORE_INDEX) { loss += __logf(den1) - __logf(num1); cnt += 1.f; }

    // 64-lane wave reduction
    #pragma unroll
    for (int off = 32; off > 0; off >>= 1) {
        loss += __shfl_down(loss, off);
        cnt  += __shfl_down(cnt,  off);
    }

    __shared__ float s_loss[4];
    __shared__ float s_cnt[4];
    const int wave = tid >> 6;
    const int lane = tid & 63;
    if (lane == 0) { s_loss[wave] = loss; s_cnt[wave] = cnt; }
    __syncthreads();
    if (tid == 0) {
        float2 pr;
        pr.x = s_loss[0] + s_loss[1] + s_loss[2] + s_loss[3];
        pr.y = s_cnt[0]  + s_cnt[1]  + s_cnt[2]  + s_cnt[3];
        partial[blockIdx.x] = pr;
    }
}

// Reduce 2048 float2 partials -> scalar loss. One block of 256 threads;
// each thread reads 8 partials via four float4 loads (tid*64B, aligned).
__global__ __launch_bounds__(256) void uni_ce_final(
    const float2* __restrict__ partial,
    float*        __restrict__ out)
{
    const int tid = threadIdx.x;
    const float4 q0 = *(const float4*)(partial + tid * 8);
    const float4 q1 = *(const float4*)(partial + tid * 8 + 2);
    const float4 q2 = *(const float4*)(partial + tid * 8 + 4);
    const float4 q3 = *(const float4*)(partial + tid * 8 + 6);
    float loss = q0.x + q0.z + q1.x + q1.z + q2.x + q2.z + q3.x + q3.z;
    float cnt  = q0.y + q0.w + q1.y + q1.w + q2.y + q2.w + q3.y + q3.w;

    #pragma unroll
    for (int off = 32; off > 0; off >>= 1) {
        loss += __shfl_down(loss, off);
        cnt  += __shfl_down(cnt,  off);
    }

    __shared__ float s_loss[4];
    __shared__ float s_cnt[4];
    const int wave = tid >> 6;
    const int lane = tid & 63;
    if (lane == 0) { s_loss[wave] = loss; s_cnt[wave] = cnt; }
    __syncthreads();
    if (tid == 0) {
        const float L = s_loss[0] + s_loss[1] + s_loss[2] + s_loss[3];
        const float C = s_cnt[0]  + s_cnt[1]  + s_cnt[2]  + s_cnt[3];
        out[0] = L / fmaxf(C, 1.0f);
    }
}

extern "C" void kernel_launch(void* const* d_in, const int* in_sizes, int n_in,
                              void* d_out, int out_size, void* d_ws, size_t ws_size,
                              hipStream_t stream) {
    const float* inp = (const float*)d_in[0];
    const int*   tgt = (const int*)d_in[1];
    const int*   gid = (const int*)d_in[2];
    float* out = (float*)d_out;
    float2* partial = (float2*)d_ws;   // 2048 float2 = 16 KiB, written before read

    const int threads = 256;
    uni_ce_main<<<NBLOCKS, threads, 0, stream>>>(inp, tgt, gid, partial);
    uni_ce_final<<<1, threads, 0, stream>>>(partial, out);
}